// Round 14
// baseline (141.607 us; speedup 1.0000x reference)
//
#include <hip/hip_runtime.h>
#include <hip/hip_bf16.h>

// SparseLinear forward as DENSE bf16 MFMA GEMM:  C = A * B^T + bias (4096^3).
// R14 = R13 taken to its sync endpoint: ONE counted vmcnt + ONE barrier per
// K-tile. B becomes a 3-deep ring (slot (t+2)%3 staged during tile t; its
// readers were tile t-1, fenced by tile t's entry barrier) so the end-P1
// WAR barrier of R13 is unnecessary. A stays 2-deep. LDS = 64KB A + 96KB B
// = 160KB (gfx950 max; 1 block/CU as before). Ledger: per tile issue
// A(t+1) then B(t+2); entry vmcnt(4) retains exactly B(t+1); prologue
// B(0),A(0),B(1); final tile vmcnt(0). K-complete phases with register-held
// B-frags, zero-conflict granule-XOR swizzle, setprio, fused-bias epilogue.

typedef __bf16 bf16x8 __attribute__((ext_vector_type(8)));
typedef float f32x4 __attribute__((ext_vector_type(4)));

constexpr int M = 4096;   // T*B
constexpr int N = 4096;   // C_OUT
constexpr int K = 4096;   // C_IN
constexpr int BM = 256, BN = 256, BK = 64;
constexpr int NT = K / BK;          // 64 K-tiles
constexpr int A_BUF = 16384;        // elems per A buffer (2 units: k0,k1)
constexpr int B_BASE = 32768;       // elem offset of B region
constexpr int B_SLOT = 16384;       // elems per B slot (2 units: k0,k1)

__device__ __forceinline__ unsigned short f2bf_rne(float f) {
    unsigned int u = __float_as_uint(f);
    u += 0x7fffu + ((u >> 16) & 1u);   // round-to-nearest-even
    return (unsigned short)(u >> 16);
}

// Fused convert: x -> Abf and w -> Bbf in one launch.
__global__ __launch_bounds__(256) void cvt_both(const float* __restrict__ x,
                                                const float* __restrict__ w,
                                                unsigned short* __restrict__ Abf,
                                                unsigned short* __restrict__ Bbf) {
    const int n8 = (M * K) / 8;
    int idx = blockIdx.x * blockDim.x + threadIdx.x;
    int stride = gridDim.x * blockDim.x;
    for (int i = idx; i < 2 * n8; i += stride) {
        const float* src;
        unsigned short* dst;
        if (i < n8) { long b = (long)i * 8;        src = x + b; dst = Abf + b; }
        else        { long b = (long)(i - n8) * 8; src = w + b; dst = Bbf + b; }
        float4 v0 = *(const float4*)(src);
        float4 v1 = *(const float4*)(src + 4);
        ushort4 r0, r1;
        r0.x = f2bf_rne(v0.x); r0.y = f2bf_rne(v0.y);
        r0.z = f2bf_rne(v0.z); r0.w = f2bf_rne(v0.w);
        r1.x = f2bf_rne(v1.x); r1.y = f2bf_rne(v1.y);
        r1.z = f2bf_rne(v1.z); r1.w = f2bf_rne(v1.w);
        *(ushort4*)(dst) = r0;
        *(ushort4*)(dst + 4) = r1;
    }
}

// Stage one k-half unit ([256 rows][32 k] = 16 KiB, 2 global_load_lds) into
// LDS (linear dest, pre-swizzled global source: cg ^= (row>>1)&3).
__device__ __forceinline__ void stage_unit(const unsigned short* __restrict__ g,
                                           size_t grow0, int kcol0,
                                           unsigned short* unitbase,
                                           int tid, int wave) {
#pragma unroll
    for (int i = 0; i < 2; ++i) {
        const int row = i * 128 + (tid >> 2);
        const int cg  = (tid & 3) ^ ((row >> 1) & 3);
        const unsigned short* src = g + (grow0 + (size_t)row) * (size_t)K
                                      + (size_t)(kcol0 + cg * 8);
        unsigned short* dst = unitbase + i * 4096 + wave * 512;
        __builtin_amdgcn_global_load_lds(
            (const __attribute__((address_space(1))) void*)src,
            (__attribute__((address_space(3))) void*)dst, 16, 0, 0);
    }
}

// One m-pair phase: 2 a-frags (both k-units) x held b[4][2], 16 MFMA.
#define PHASE(MP)                                                              \
    {                                                                          \
        bf16x8 a0k0 = *(const bf16x8*)(pA0 + (2*(MP)) * 512);                  \
        bf16x8 a1k0 = *(const bf16x8*)(pA0 + (2*(MP)+1) * 512);                \
        bf16x8 a0k1 = *(const bf16x8*)(pA1 + (2*(MP)) * 512);                  \
        bf16x8 a1k1 = *(const bf16x8*)(pA1 + (2*(MP)+1) * 512);                \
        __builtin_amdgcn_s_setprio(1);                                         \
        _Pragma("unroll")                                                      \
        for (int n = 0; n < 4; ++n) {                                          \
            acc[2*(MP)][n]   = __builtin_amdgcn_mfma_f32_16x16x32_bf16(        \
                a0k0, b[n][0], acc[2*(MP)][n], 0, 0, 0);                       \
            acc[2*(MP)+1][n] = __builtin_amdgcn_mfma_f32_16x16x32_bf16(        \
                a1k0, b[n][0], acc[2*(MP)+1][n], 0, 0, 0);                     \
        }                                                                      \
        _Pragma("unroll")                                                      \
        for (int n = 0; n < 4; ++n) {                                          \
            acc[2*(MP)][n]   = __builtin_amdgcn_mfma_f32_16x16x32_bf16(        \
                a0k1, b[n][1], acc[2*(MP)][n], 0, 0, 0);                       \
            acc[2*(MP)+1][n] = __builtin_amdgcn_mfma_f32_16x16x32_bf16(        \
                a1k1, b[n][1], acc[2*(MP)+1][n], 0, 0, 0);                     \
        }                                                                      \
        __builtin_amdgcn_s_setprio(0);                                         \
    }

__global__ __launch_bounds__(512, 2) void gemm_lean1b(
    const unsigned short* __restrict__ A,   // [M][K] bf16 bits
    const unsigned short* __restrict__ B,   // [N][K] bf16 bits
    const float* __restrict__ bias,         // [N]
    float* __restrict__ C)                  // [M][N] fp32
{
    __shared__ unsigned short lds[81920];   // 160 KiB: A 2-deep + B 3-deep

    // XCD-aware bijective swizzle: 256 wgs, 256 % 8 == 0
    const int wg = blockIdx.x;
    const int s  = ((wg & 7) << 5) | (wg >> 3);
    const int bm = s >> 4, bn = s & 15;
    const size_t brow = (size_t)bm * BM;
    const size_t bcol = (size_t)bn * BN;

    const int tid  = threadIdx.x;
    const int wave = tid >> 6;
    const int lane = tid & 63;
    const int wr = wave >> 2;       // 0..1  (2 M-waves, 128 rows each)
    const int wc = wave & 3;        // 0..3  (4 N-waves, 64 cols each)
    const int lr = lane & 15;       // fragment row-in-16
    const int kg = lane >> 4;       // k-group 0..3

    const int a_row0 = wr * 128 + lr;
    const int b_row0 = wc * 64 + lr;
    const int aoff = a_row0 * 32 + ((kg ^ ((a_row0 >> 1) & 3)) << 3);
    const int boff = b_row0 * 32 + ((kg ^ ((b_row0 >> 1) & 3)) << 3);

    f32x4 acc[8][4];
#pragma unroll
    for (int m = 0; m < 8; ++m)
#pragma unroll
        for (int n = 0; n < 4; ++n)
            acc[m][n] = (f32x4){0.f, 0.f, 0.f, 0.f};

    // ---- prologue: B(0), A(0), B(1) = 12 loads (B(1) newest) ----
    stage_unit(B, bcol, 0,       lds + B_BASE, tid, wave);
    stage_unit(B, bcol, 32,      lds + B_BASE + 8192, tid, wave);
    stage_unit(A, brow, 0,       lds, tid, wave);
    stage_unit(A, brow, 32,      lds + 8192, tid, wave);
    stage_unit(B, bcol, BK,      lds + B_BASE + B_SLOT, tid, wave);
    stage_unit(B, bcol, BK + 32, lds + B_BASE + B_SLOT + 8192, tid, wave);

    int bs = 0;   // B ring slot of tile t
    for (int t = 0; t < NT; ++t) {
        const bool pf1 = (t + 1) < NT;
        const bool pf2 = (t + 2) < NT;

        // Entry wait: A(t)+B(t) landed; B(t+1)'s 4 loads (newest) stay in
        // flight. Entry barrier fences ALL previous-tile LDS reads (WAR for
        // every region staged this tile).
        if (pf1) { asm volatile("s_waitcnt vmcnt(4)" ::: "memory"); }
        else     { asm volatile("s_waitcnt vmcnt(0)" ::: "memory"); }
        __builtin_amdgcn_s_barrier();

        unsigned short* ab = lds + (t & 1) * A_BUF;
        unsigned short* ao = lds + ((t & 1) ^ 1) * A_BUF;   // A stage target
        unsigned short* bb = lds + B_BASE + bs * B_SLOT;
        const int bs2 = (bs + 2 >= 3) ? bs - 1 : bs + 2;    // (t+2)%3
        unsigned short* b2 = lds + B_BASE + bs2 * B_SLOT;   // B stage target

        const unsigned short* pA0 = ab + aoff;
        const unsigned short* pA1 = ab + 8192 + aoff;

        // ===== P1: load ALL B-frags (held whole tile) + m-pair 0 =====
        bf16x8 b[4][2];
#pragma unroll
        for (int n = 0; n < 4; ++n) {
            b[n][0] = *(const bf16x8*)(bb + boff + n * 512);
            b[n][1] = *(const bf16x8*)(bb + 8192 + boff + n * 512);
        }
        if (pf1) stage_unit(A, brow, (t + 1) * BK, ao, tid, wave);
        PHASE(0)

        // ===== P2..P4: free-run (no barriers) =====
        if (pf1) stage_unit(A, brow, (t + 1) * BK + 32, ao + 8192, tid, wave);
        PHASE(1)
        if (pf2) stage_unit(B, bcol, (t + 2) * BK, b2, tid, wave);
        PHASE(2)
        if (pf2) stage_unit(B, bcol, (t + 2) * BK + 32, b2 + 8192, tid, wave);
        PHASE(3)

        bs = (bs + 1 >= 3) ? 0 : bs + 1;
    }

    // ---- epilogue: C/D layout col=lane&15, row=(lane>>4)*4+j; fused bias ----
#pragma unroll
    for (int n = 0; n < 4; ++n) {
        const size_t col = bcol + wc * 64 + n * 16 + lr;
        const float bs_ = bias[col];
#pragma unroll
        for (int m = 0; m < 8; ++m) {
            const size_t row0 = brow + (size_t)wr * 128 + m * 16 + kg * 4;
#pragma unroll
            for (int j = 0; j < 4; ++j) {
                C[(row0 + j) * N + col] = acc[m][n][j] + bs_;
            }
        }
    }
}

extern "C" void kernel_launch(void* const* d_in, const int* in_sizes, int n_in,
                              void* d_out, int out_size, void* d_ws, size_t ws_size,
                              hipStream_t stream) {
    const float* x    = (const float*)d_in[0];   // [T,B,C_IN] = [M,K]
    const float* w    = (const float*)d_in[1];   // [C_OUT,C_IN] = [N,K]
    const float* bias = (const float*)d_in[2];   // [N]
    float* out = (float*)d_out;                  // [M,N]

    unsigned short* Abf = (unsigned short*)d_ws;           // 32 MiB
    unsigned short* Bbf = Abf + (size_t)M * K;             // 32 MiB

    cvt_both<<<4096, 256, 0, stream>>>(x, w, Abf, Bbf);

    gemm_lean1b<<<dim3((M / BM) * (N / BN)), 512, 0, stream>>>(Abf, Bbf, bias, out);
}